// Round 1
// baseline (4757.066 us; speedup 1.0000x reference)
//
#include <hip/hip_runtime.h>
#include <cstdint>
#include <cstddef>

#define S_LEN   1024
#define B_SZ    2
#define H_DIM   512
#define N_HEADS 8
#define Q_DIM   64
#define L_LAYERS 6
#define V_SIZE  50257
#define EPS_LN  1e-5f

// h[b,s,:] = embedding[x[b,s],:] + pos_enc[s,:]
__global__ __launch_bounds__(128) void embed_kernel(
    const int* __restrict__ x, const float* __restrict__ emb,
    const float* __restrict__ pos, float* __restrict__ h)
{
  const int r = blockIdx.x;            // r = b*S + s
  const int s = r & (S_LEN - 1);
  const int tok = x[r];
  const float4* e = reinterpret_cast<const float4*>(emb + (size_t)tok * H_DIM);
  const float4* p = reinterpret_cast<const float4*>(pos + (size_t)s * H_DIM);
  float4* o = reinterpret_cast<float4*>(h + (size_t)r * H_DIM);
  const int t = threadIdx.x;           // 128 threads * 4 floats = 512
  float4 ev = e[t], pv = p[t];
  o[t] = make_float4(ev.x + pv.x, ev.y + pv.y, ev.z + pv.z, ev.w + pv.w);
}

// C = A @ W^T (+bias) (+relu) (+add). A:[M,K] row-major, W:[Nc,K] row-major.
// MODE: 0 = plain, 1 = relu(bias applied before relu, add after), 2 = scatter
// output to [B,N,S,Q] layout (for q/k/v).
template<int BM, int BN, int TM, int TN, int MODE>
__global__ __launch_bounds__(256) void gemm_bt(
    const float* __restrict__ A, const float* __restrict__ W,
    const float* __restrict__ bias, const float* __restrict__ add,
    float* __restrict__ C, int M, int Nc, int K)
{
  constexpr int BK = 16;
  __shared__ float As[BK][BM];
  __shared__ float Ws[BK][BN];
  const int tid = threadIdx.x;
  constexpr int NTX = BN / TN;
  const int tx = tid % NTX;
  const int ty = tid / NTX;
  const int bm = blockIdx.y * BM;
  const int bn = blockIdx.x * BN;
  float acc[TM][TN] = {};

  const int nk = K / BK;
  for (int kt = 0; kt < nk; ++kt) {
    const int k0 = kt * BK;
    for (int i = tid; i < BM * 4; i += 256) {     // BM*BK/4 float4s
      int row = i >> 2;
      int c4  = (i & 3) * 4;
      float4 va = *reinterpret_cast<const float4*>(&A[(size_t)(bm + row) * K + k0 + c4]);
      As[c4 + 0][row] = va.x; As[c4 + 1][row] = va.y;
      As[c4 + 2][row] = va.z; As[c4 + 3][row] = va.w;
    }
    for (int i = tid; i < BN * 4; i += 256) {
      int row = i >> 2;
      int c4  = (i & 3) * 4;
      float4 vb;
      if (bn + row < Nc)
        vb = *reinterpret_cast<const float4*>(&W[(size_t)(bn + row) * K + k0 + c4]);
      else
        vb = make_float4(0.f, 0.f, 0.f, 0.f);
      Ws[c4 + 0][row] = vb.x; Ws[c4 + 1][row] = vb.y;
      Ws[c4 + 2][row] = vb.z; Ws[c4 + 3][row] = vb.w;
    }
    __syncthreads();
    #pragma unroll
    for (int k = 0; k < BK; ++k) {
      float ar[TM], br[TN];
      #pragma unroll
      for (int i4 = 0; i4 < TM / 4; ++i4)
        *reinterpret_cast<float4*>(&ar[i4 * 4]) =
            *reinterpret_cast<const float4*>(&As[k][ty * TM + i4 * 4]);
      #pragma unroll
      for (int j4 = 0; j4 < TN / 4; ++j4)
        *reinterpret_cast<float4*>(&br[j4 * 4]) =
            *reinterpret_cast<const float4*>(&Ws[k][tx * TN + j4 * 4]);
      #pragma unroll
      for (int i = 0; i < TM; ++i)
        #pragma unroll
        for (int j = 0; j < TN; ++j)
          acc[i][j] = fmaf(ar[i], br[j], acc[i][j]);
    }
    __syncthreads();
  }

  #pragma unroll
  for (int i = 0; i < TM; ++i) {
    const int r = bm + ty * TM + i;
    #pragma unroll
    for (int j4 = 0; j4 < TN / 4; ++j4) {
      const int c = bn + tx * TN + j4 * 4;
      float vv[4];
      #pragma unroll
      for (int l = 0; l < 4; ++l) {
        vv[l] = acc[i][j4 * 4 + l];
        if (bias && c + l < Nc) vv[l] += bias[c + l];
        if (MODE == 1) vv[l] = fmaxf(vv[l], 0.f);
        if (add && c + l < Nc) vv[l] += add[(size_t)r * Nc + c + l];
      }
      if (MODE == 2) {
        // r = b*1024+s ; c = head*64+qd ; dst[(b*8+head)*65536 + s*64 + qd]
        const int b = r >> 10, s = r & 1023;
        const int head = c >> 6, qd = c & 63;
        *reinterpret_cast<float4*>(
            &C[((size_t)(b * N_HEADS + head) << 16) + (s << 6) + qd]) =
            make_float4(vv[0], vv[1], vv[2], vv[3]);
      } else if (c + 4 <= Nc) {
        *reinterpret_cast<float4*>(&C[(size_t)r * Nc + c]) =
            make_float4(vv[0], vv[1], vv[2], vv[3]);
      } else {
        for (int l = 0; l < 4; ++l)
          if (c + l < Nc) C[(size_t)r * Nc + c + l] = vv[l];
      }
    }
  }
}

// Fused: scores = Q @ kT (reshape quirk) * 0.125, softmax over BATCH axis
// (b=0 vs b=1), causal mask AFTER softmax (masked -> 1e-9), store attn[B,N,S,S].
__global__ __launch_bounds__(256) void attn_scores(
    const float* __restrict__ q, const float* __restrict__ k,
    float* __restrict__ attn)
{
  const int tt = blockIdx.x, st = blockIdx.y, n = blockIdx.z;
  __shared__ float Qs[64][68];   // [s][q], padded to kill stride-64 bank conflicts
  __shared__ float Ks[64][64];   // [q][t-t0]
  const int tid = threadIdx.x;
  const int tx = tid & 15, ty = tid >> 4;
  const int s0 = st * 64, t0 = tt * 64;
  float acc[2][4][4] = {};
  for (int b = 0; b < 2; ++b) {
    const float* qbase = q + ((size_t)(b * N_HEADS + n) << 16);
    const float* kbase = k + ((size_t)(b * N_HEADS + n) << 16);
    for (int i = tid; i < 64 * 16; i += 256) {
      const int row = i >> 4, c4 = (i & 15) * 4;
      *reinterpret_cast<float4*>(&Qs[row][c4]) =
          *reinterpret_cast<const float4*>(&qbase[(size_t)(s0 + row) * 64 + c4]);
      // kT[q][t0+j] = k[q*16 + tt][j]  (reshape quirk; t0>>6 == tt)
      *reinterpret_cast<float4*>(&Ks[row][c4]) =
          *reinterpret_cast<const float4*>(&kbase[(size_t)(row * 16 + tt) * 64 + c4]);
    }
    __syncthreads();
    #pragma unroll 8
    for (int kq = 0; kq < 64; ++kq) {
      const float4 kv = *reinterpret_cast<const float4*>(&Ks[kq][tx * 4]);
      #pragma unroll
      for (int i = 0; i < 4; ++i) {
        const float qv = Qs[ty * 4 + i][kq];
        acc[b][i][0] = fmaf(qv, kv.x, acc[b][i][0]);
        acc[b][i][1] = fmaf(qv, kv.y, acc[b][i][1]);
        acc[b][i][2] = fmaf(qv, kv.z, acc[b][i][2]);
        acc[b][i][3] = fmaf(qv, kv.w, acc[b][i][3]);
      }
    }
    __syncthreads();
  }
  const float scale = 0.125f;   // 1/sqrt(64)
  #pragma unroll
  for (int i = 0; i < 4; ++i) {
    const int s = s0 + ty * 4 + i;
    float r0[4], r1[4];
    #pragma unroll
    for (int j = 0; j < 4; ++j) {
      const int t = t0 + tx * 4 + j;
      const float x0 = acc[0][i][j] * scale, x1 = acc[1][i][j] * scale;
      const float m = fmaxf(x0, x1);
      const float e0 = __expf(x0 - m), e1 = __expf(x1 - m);
      const float inv = 1.f / (e0 + e1);
      float a0 = e0 * inv, a1 = e1 * inv;
      if (t > s) { a0 = 1e-9f; a1 = 1e-9f; }
      r0[j] = a0; r1[j] = a1;
    }
    const size_t base0 = ((size_t)n * S_LEN + s) * S_LEN + t0 + tx * 4;
    const size_t base1 = ((size_t)(N_HEADS + n) * S_LEN + s) * S_LEN + t0 + tx * 4;
    *reinterpret_cast<float4*>(&attn[base0]) = make_float4(r0[0], r0[1], r0[2], r0[3]);
    *reinterpret_cast<float4*>(&attn[base1]) = make_float4(r1[0], r1[1], r1[2], r1[3]);
  }
}

// res[b,n,s,:] = attn[b,n,s,:] @ v[b,n,:,:]; written directly in concat layout
// cat[b, s, n*64+qd]
__global__ __launch_bounds__(256) void attn_v(
    const float* __restrict__ attn, const float* __restrict__ v,
    float* __restrict__ cat)
{
  const int st = blockIdx.x, bn = blockIdx.y;
  const int b = bn >> 3, n = bn & 7;
  __shared__ float As[64][68];   // [s][t] padded
  __shared__ float Vs[64][64];   // [t][qd]
  const int tid = threadIdx.x;
  const int tx = tid & 15, ty = tid >> 4;
  const int s0 = st * 64;
  const float* abase = attn + (size_t)bn * S_LEN * S_LEN;
  const float* vbase = v + ((size_t)bn << 16);
  float acc[4][4] = {};
  for (int tt = 0; tt < 16; ++tt) {
    for (int i = tid; i < 64 * 16; i += 256) {
      const int row = i >> 4, c4 = (i & 15) * 4;
      *reinterpret_cast<float4*>(&As[row][c4]) =
          *reinterpret_cast<const float4*>(&abase[(size_t)(s0 + row) * S_LEN + tt * 64 + c4]);
      *reinterpret_cast<float4*>(&Vs[row][c4]) =
          *reinterpret_cast<const float4*>(&vbase[(size_t)(tt * 64 + row) * 64 + c4]);
    }
    __syncthreads();
    #pragma unroll 8
    for (int t = 0; t < 64; ++t) {
      const float4 vv = *reinterpret_cast<const float4*>(&Vs[t][tx * 4]);
      #pragma unroll
      for (int i = 0; i < 4; ++i) {
        const float av = As[ty * 4 + i][t];
        acc[i][0] = fmaf(av, vv.x, acc[i][0]);
        acc[i][1] = fmaf(av, vv.y, acc[i][1]);
        acc[i][2] = fmaf(av, vv.z, acc[i][2]);
        acc[i][3] = fmaf(av, vv.w, acc[i][3]);
      }
    }
    __syncthreads();
  }
  #pragma unroll
  for (int i = 0; i < 4; ++i) {
    const int s = s0 + ty * 4 + i;
    const size_t idx = ((size_t)(b * S_LEN) + s) * H_DIM + n * 64 + tx * 4;
    *reinterpret_cast<float4*>(&cat[idx]) =
        make_float4(acc[i][0], acc[i][1], acc[i][2], acc[i][3]);
  }
}

// out = (optional add +) LayerNorm(in) * gamma + beta ; row length H=512.
__global__ __launch_bounds__(256) void ln_kernel(
    const float* __restrict__ in, const float* __restrict__ gamma,
    const float* __restrict__ beta, const float* __restrict__ add,
    float* __restrict__ out)
{
  const int row = blockIdx.x;
  const int tid = threadIdx.x;
  const float* x = in + (size_t)row * H_DIM;
  const float2 v = *reinterpret_cast<const float2*>(&x[tid * 2]);
  float s  = v.x + v.y;
  float sq = v.x * v.x + v.y * v.y;
  #pragma unroll
  for (int off = 32; off > 0; off >>= 1) {
    s  += __shfl_down(s, off, 64);
    sq += __shfl_down(sq, off, 64);
  }
  __shared__ float red[8];
  if ((tid & 63) == 0) { red[(tid >> 6) * 2] = s; red[(tid >> 6) * 2 + 1] = sq; }
  __syncthreads();
  const float ts  = red[0] + red[2] + red[4] + red[6];
  const float tsq = red[1] + red[3] + red[5] + red[7];
  const float mean = ts * (1.f / H_DIM);
  const float var  = tsq * (1.f / H_DIM) - mean * mean;
  const float inv  = 1.f / sqrtf(var + EPS_LN);
  const float2 g  = *reinterpret_cast<const float2*>(&gamma[tid * 2]);
  const float2 bb = *reinterpret_cast<const float2*>(&beta[tid * 2]);
  float2 o;
  o.x = (v.x - mean) * inv * g.x + bb.x;
  o.y = (v.y - mean) * inv * g.y + bb.y;
  if (add) {
    const float2 av = *reinterpret_cast<const float2*>(&add[(size_t)row * H_DIM + tid * 2]);
    o.x += av.x; o.y += av.y;
  }
  *reinterpret_cast<float2*>(&out[(size_t)row * H_DIM + tid * 2]) = o;
}

extern "C" void kernel_launch(void* const* d_in, const int* in_sizes, int n_in,
                              void* d_out, int out_size, void* d_ws, size_t ws_size,
                              hipStream_t stream)
{
  const int*   x    = (const int*)  d_in[0];
  const float* emb  = (const float*)d_in[1];
  const float* pos  = (const float*)d_in[2];
  const float* lng  = (const float*)d_in[3];
  const float* lnb  = (const float*)d_in[4];
  const float* Wq   = (const float*)d_in[5];
  const float* Wk   = (const float*)d_in[6];
  const float* Wv   = (const float*)d_in[7];
  const float* Wp   = (const float*)d_in[8];
  const float* bp   = (const float*)d_in[9];
  const float* W1   = (const float*)d_in[10];
  const float* b1   = (const float*)d_in[11];
  const float* W2   = (const float*)d_in[12];
  const float* b2   = (const float*)d_in[13];
  const float* Wlm  = (const float*)d_in[14];
  const float* blm  = (const float*)d_in[15];
  float* out = (float*)d_out;

  char* ws = (char*)d_ws;
  const size_t MB = 1024 * 1024;
  float* h    = (float*)(ws + 0 * MB);    // [2048,512]   4MB
  float* q    = (float*)(ws + 4 * MB);    // [B,N,S,Q]    4MB
  float* kk   = (float*)(ws + 8 * MB);    // [B,N,S,Q]    4MB
  float* vv   = (float*)(ws + 12 * MB);   // [B,N,S,Q]    4MB
  float* attn = (float*)(ws + 16 * MB);   // [B,N,S,S]   64MB
  float* cat  = (float*)(ws + 80 * MB);   // [2048,512]   4MB
  float* proj = (float*)(ws + 84 * MB);   // [2048,512]   4MB
  float* a    = (float*)(ws + 88 * MB);   // [2048,512]   4MB
  float* lna  = (float*)(ws + 92 * MB);   // [2048,512]   4MB
  float* mlp1 = (float*)(ws + 96 * MB);   // [2048,2048] 16MB
  (void)in_sizes; (void)n_in; (void)out_size; (void)ws_size;

  const int M = B_SZ * S_LEN;  // 2048

  embed_kernel<<<M, 128, 0, stream>>>(x, emb, pos, h);

  const dim3 g64(512 / 64, M / 64);
  for (int i = 0; i < L_LAYERS; ++i) {
    const float* Wqi = Wq + (size_t)i * 512 * 512;
    const float* Wki = Wk + (size_t)i * 512 * 512;
    const float* Wvi = Wv + (size_t)i * 512 * 512;
    const float* Wpi = Wp + (size_t)i * 512 * 512;
    const float* bpi = bp + (size_t)i * 512;
    const float* W1i = W1 + (size_t)i * 2048 * 512;
    const float* b1i = b1 + (size_t)i * 2048;
    const float* W2i = W2 + (size_t)i * 512 * 2048;
    const float* b2i = b2 + (size_t)i * 512;

    gemm_bt<64, 64, 4, 4, 2><<<g64, 256, 0, stream>>>(h, Wqi, nullptr, nullptr, q,  M, 512, 512);
    gemm_bt<64, 64, 4, 4, 2><<<g64, 256, 0, stream>>>(h, Wki, nullptr, nullptr, kk, M, 512, 512);
    gemm_bt<64, 64, 4, 4, 2><<<g64, 256, 0, stream>>>(h, Wvi, nullptr, nullptr, vv, M, 512, 512);

    attn_scores<<<dim3(16, 16, 8), 256, 0, stream>>>(q, kk, attn);
    attn_v<<<dim3(16, 16), 256, 0, stream>>>(attn, vv, cat);

    gemm_bt<64, 64, 4, 4, 0><<<g64, 256, 0, stream>>>(cat, Wpi, bpi, nullptr, proj, M, 512, 512);
    ln_kernel<<<M, 256, 0, stream>>>(proj, lng, lnb, h, a);      // a = h + LN(proj)
    gemm_bt<128, 128, 8, 8, 1><<<dim3(2048 / 128, M / 128), 256, 0, stream>>>(
        a, W1i, b1i, nullptr, mlp1, M, 2048, 512);               // relu(a@W1^T+b1)
    ln_kernel<<<M, 256, 0, stream>>>(a, lng, lnb, nullptr, lna); // lna = LN(a)
    gemm_bt<64, 64, 4, 4, 0><<<g64, 256, 0, stream>>>(
        mlp1, W2i, b2i, lna, h, M, 512, 2048);                   // h = mlp2 + lna
  }

  gemm_bt<128, 128, 8, 8, 0><<<dim3((V_SIZE + 127) / 128, M / 128), 256, 0, stream>>>(
      h, Wlm, blm, nullptr, out, M, V_SIZE, 512);
}